// Round 6
// baseline (163.821 us; speedup 1.0000x reference)
//
#include <hip/hip_runtime.h>
#include <hip/hip_bf16.h>
#include <stdint.h>

// Problem: B=2, S=2048, D=512, H=8, DK=64
#define S_LEN 2048
#define D_MOD 512
#define N_H   8
#define D_K   64

typedef short v8s __attribute__((ext_vector_type(8)));
typedef short v4s __attribute__((ext_vector_type(4)));
typedef float v4f __attribute__((ext_vector_type(4)));

__device__ __forceinline__ short f2bf(float f) {
  union { float f; unsigned u; } a; a.f = f;
  unsigned u = a.u;
  u += 0x7fffu + ((u >> 16) & 1u);   // round-to-nearest-even
  return (short)(u >> 16);
}

__device__ __forceinline__ v4f mfma16(v8s a, v8s b, v4f c) {
  return __builtin_amdgcn_mfma_f32_16x16x32_bf16(a, b, c, 0, 0, 0);
}
__device__ __forceinline__ v4f mfma16x16(v4s a, v4s b, v4f c) {
  return __builtin_amdgcn_mfma_f32_16x16x16bf16_1k(a, b, c, 0, 0, 0);
}

// ---------------------------------------------------------------------------
// prep: fused fp32->bf16 convert (q,k,v,Wq,Wo) + mask bit-pack.
// blocks [0,6656): cvt (4 floats/thread). blocks [6656,6912): maskpack.
// ---------------------------------------------------------------------------
__global__ __launch_bounds__(256) void prep_kernel(
    const float* __restrict__ q, const float* __restrict__ k,
    const float* __restrict__ v, const float* __restrict__ Wq,
    const float* __restrict__ Wo, const int* __restrict__ mask,
    short* __restrict__ qb, short* __restrict__ kb, short* __restrict__ vb,
    short* __restrict__ Wqb, short* __restrict__ Wob,
    unsigned long long* __restrict__ mp)
{
  unsigned bx = blockIdx.x;
  if (bx < 6656u) {
    unsigned g = bx * 256 + threadIdx.x;   // group id, 1703936 total
    const float* src; short* dst; unsigned off;
    if (g < 524288u)        { src = q;  dst = qb;  off = g; }
    else if (g < 1048576u)  { src = k;  dst = kb;  off = g - 524288u; }
    else if (g < 1572864u)  { src = v;  dst = vb;  off = g - 1048576u; }
    else if (g < 1638400u)  { src = Wq; dst = Wqb; off = g - 1572864u; }
    else                    { src = Wo; dst = Wob; off = g - 1638400u; }
    float4 x = ((const float4*)src)[off];
    v4s p; p.x = f2bf(x.x); p.y = f2bf(x.y); p.z = f2bf(x.z); p.w = f2bf(x.w);
    ((v4s*)dst)[off] = p;
  } else {
    int id = (bx - 6656u) * 256 + threadIdx.x;     // 0..65535
    const int4* m4 = (const int4*)(mask + (size_t)id * 64);
    unsigned long long w = 0ull;
#pragma unroll
    for (int j = 0; j < 16; j++) {
      int4 mv = m4[j];
      w |= (unsigned long long)(mv.x != 0) << (j * 4 + 0);
      w |= (unsigned long long)(mv.y != 0) << (j * 4 + 1);
      w |= (unsigned long long)(mv.z != 0) << (j * 4 + 2);
      w |= (unsigned long long)(mv.w != 0) << (j * 4 + 3);
    }
    mp[id] = w;
  }
}

// ---------------------------------------------------------------------------
// proj: C = A @ Wq^T for A in {qb,kb,vb} (z = blockIdx.z), all-bf16 inputs,
// VGPR-prefetch pipelined. Outputs QP/KP [B,H,S,DK], VT [B,H,DK,S].
// ---------------------------------------------------------------------------
__global__ __launch_bounds__(256) void proj_kernel(
    const short* __restrict__ qb, const short* __restrict__ kb,
    const short* __restrict__ vb, const short* __restrict__ Wqb,
    short* __restrict__ QP, short* __restrict__ KP, short* __restrict__ VT)
{
  const int z = blockIdx.z;
  const short* __restrict__ A = (z == 0) ? qb : ((z == 1) ? kb : vb);
  const int m0 = blockIdx.x * 64, n0 = blockIdx.y * 64;
  const int tid = threadIdx.x;
  const int wave = tid >> 6, lane = tid & 63;
  const int quad = lane >> 4, l15 = lane & 15;
  const int wm = wave >> 1, wn = wave & 1;
  __shared__ short As[64][72];
  __shared__ short Bs[64][72];
  v4f acc[2][2];
#pragma unroll
  for (int i = 0; i < 2; i++)
#pragma unroll
    for (int j = 0; j < 2; j++) acc[i][j] = (v4f){0.f, 0.f, 0.f, 0.f};

  v8s a8[2], b8[2];
#pragma unroll
  for (int i = 0; i < 2; i++) {
    int fi = tid + i * 256, r = fi >> 3, c = (fi & 7) << 3;
    a8[i] = *(const v8s*)&A[(m0 + r) * 512 + c];
    b8[i] = *(const v8s*)&Wqb[(n0 + r) * 512 + c];
  }

  for (int kk = 0; kk < 512; kk += 64) {
    __syncthreads();
#pragma unroll
    for (int i = 0; i < 2; i++) {
      int fi = tid + i * 256, r = fi >> 3, c = (fi & 7) << 3;
      *(v8s*)&As[r][c] = a8[i];
      *(v8s*)&Bs[r][c] = b8[i];
    }
    __syncthreads();
    if (kk + 64 < 512) {
#pragma unroll
      for (int i = 0; i < 2; i++) {
        int fi = tid + i * 256, r = fi >> 3, c = (fi & 7) << 3;
        a8[i] = *(const v8s*)&A[(m0 + r) * 512 + kk + 64 + c];
        b8[i] = *(const v8s*)&Wqb[(n0 + r) * 512 + kk + 64 + c];
      }
    }
#pragma unroll
    for (int ms = 0; ms < 2; ms++)
#pragma unroll
      for (int ns = 0; ns < 2; ns++)
#pragma unroll
        for (int ks = 0; ks < 2; ks++) {
          union { v8s v; v4s h2[2]; } a, bb;
          a.h2[0]  = *(const v4s*)&As[wm * 32 + ms * 16 + l15][ks * 32 + quad * 8];
          a.h2[1]  = *(const v4s*)&As[wm * 32 + ms * 16 + l15][ks * 32 + quad * 8 + 4];
          bb.h2[0] = *(const v4s*)&Bs[wn * 32 + ns * 16 + l15][ks * 32 + quad * 8];
          bb.h2[1] = *(const v4s*)&Bs[wn * 32 + ns * 16 + l15][ks * 32 + quad * 8 + 4];
          acc[ms][ns] = mfma16(a.v, bb.v, acc[ms][ns]);
        }
  }
#pragma unroll
  for (int ms = 0; ms < 2; ms++)
#pragma unroll
    for (int ns = 0; ns < 2; ns++) {
      int mb = m0 + wm * 32 + ms * 16 + quad * 4;
      int n  = n0 + wn * 32 + ns * 16 + l15;
      int bI = mb >> 11, s = mb & 2047, hh = n >> 6, dk = n & 63;
      if (z == 2) {
        v4s pv;
        pv.x = f2bf(acc[ms][ns][0]); pv.y = f2bf(acc[ms][ns][1]);
        pv.z = f2bf(acc[ms][ns][2]); pv.w = f2bf(acc[ms][ns][3]);
        *(v4s*)&VT[((bI * N_H + hh) * D_K + dk) * S_LEN + s] = pv;
      } else {
        short* dst = (z == 0) ? QP : KP;
#pragma unroll
        for (int r = 0; r < 4; r++)
          dst[((bI * N_H + hh) * S_LEN + (s + r)) * D_K + dk] = f2bf(acc[ms][ns][r]);
      }
    }
}

// ---------------------------------------------------------------------------
// Flash attention v3: transposed-score formulation, NO P LDS round-trip.
//   S^T = mfma_16x16x32(A=K, B=Q)  -> lane holds S[q=l15][key=t'*16+quad*4+r]
//   which IS the A-fragment layout of mfma_f32_16x16x16_bf16, so
//   X += mfma_16x16x16(A=P_tile, B=V_frag) straight from registers.
// Fixed-shift softmax (exp(s/8-8)), mask = 1 u64 load/lane/phase (q=l15).
// 2-way in-block split-K (512 thr): waves 0-3 keys [0,1024), 4-7 [1024,2048),
// per-group 64x64 K/V tiles staged in LDS, VGPR-prefetched.
// Grid: (32, H, B) = 512 blocks; LDS 36.9KB.
// ---------------------------------------------------------------------------
__global__ __launch_bounds__(512, 4) void attn_kernel(
    const short* __restrict__ QP, const short* __restrict__ KP,
    const short* __restrict__ VT, const unsigned long long* __restrict__ mp,
    short* __restrict__ XP)
{
  const int h = blockIdx.y, b = blockIdx.z;
  const int tid = threadIdx.x;               // 0..511
  const int wave = tid >> 6;                 // 0..7
  const int half = wave >> 2;                // K-range half
  const int wq   = wave & 3;                 // q-subtile
  const int lane = tid & 63;
  const int quad = lane >> 4, l15 = lane & 15;
  const short* Qh = QP + ((b * N_H + h) * S_LEN) * D_K;
  const short* Kh = KP + ((b * N_H + h) * S_LEN) * D_K;
  const short* Vh = VT + ((b * N_H + h) * D_K) * S_LEN;

  // LDS: Ks 2x(64x72), Vs 2x(64x72) shorts = 36864 B.
  // Combine phase aliases [0,17408) as float CB[4][64][17].
  __shared__ char smem[36864];
  short* Ks = (short*)smem + half * 4608;
  short* Vs = (short*)(smem + 18432) + half * 4608;
  float* CB = (float*)smem;

  const int qrow = blockIdx.x * 64 + wq * 16;
  const int t8   = tid & 255;                // id within 4-wave group
  const int srow = t8 >> 2;                  // 0..63
  const int sc   = (t8 & 3) * 8;             // short offset; 2nd chunk at +32
  const int ch0  = half * 1024;              // this half's K-col base

  v8s aQ[2];                                 // Q as B-operand (n=q=l15)
#pragma unroll
  for (int ks = 0; ks < 2; ks++)
    aQ[ks] = *(const v8s*)&Qh[(qrow + l15) * D_K + ks * 32 + quad * 8];

  const float MASKP = 3.3546263e-4f;   // exp(1e-9 - 8)
  float lacc = 0.f;
  v4f accX[4];
#pragma unroll
  for (int u = 0; u < 4; u++) accX[u] = (v4f){0.f, 0.f, 0.f, 0.f};

  // prefetch tile 0 (K/V) + this lane's mask word (q = l15)
  v8s kreg0 = *(const v8s*)&Kh[(ch0 + srow) * D_K + sc];
  v8s kreg1 = *(const v8s*)&Kh[(ch0 + srow) * D_K + sc + 32];
  v8s vreg0 = *(const v8s*)&Vh[srow * S_LEN + ch0 + sc];
  v8s vreg1 = *(const v8s*)&Vh[srow * S_LEN + ch0 + sc + 32];
  unsigned long long mwc = mp[(qrow + l15) * 32 + half * 16];
  unsigned long long mwn = 0ull;

  for (int kt = 0; kt < 16; kt++) {
    __syncthreads();                       // prior compute done reading Ks/Vs
    *(v8s*)&Ks[srow * 72 + sc]      = kreg0;
    *(v8s*)&Ks[srow * 72 + sc + 32] = kreg1;
    *(v8s*)&Vs[srow * 72 + sc]      = vreg0;
    *(v8s*)&Vs[srow * 72 + sc + 32] = vreg1;
    __syncthreads();                       // tiles visible to the group

    if (kt + 1 < 16) {                     // prefetch next tile during compute
      const int c1 = ch0 + (kt + 1) * 64;
      kreg0 = *(const v8s*)&Kh[(c1 + srow) * D_K + sc];
      kreg1 = *(const v8s*)&Kh[(c1 + srow) * D_K + sc + 32];
      vreg0 = *(const v8s*)&Vh[srow * S_LEN + c1 + sc];
      vreg1 = *(const v8s*)&Vh[srow * S_LEN + c1 + sc + 32];
      mwn = mp[(qrow + l15) * 32 + half * 16 + kt + 1];
    }

    // S^T tiles: lane gets S[q=l15][key=t'*16+quad*4+r]; exp -> bf16 A-frags
    v4s pa[4];
#pragma unroll
    for (int tp = 0; tp < 4; tp++) {
      v4f s = (v4f){0.f, 0.f, 0.f, 0.f};
#pragma unroll
      for (int ks = 0; ks < 2; ks++) {
        v8s bK = *(const v8s*)&Ks[(tp * 16 + l15) * 72 + ks * 32 + quad * 8];
        s = mfma16(bK, aQ[ks], s);         // swapped operands -> S^T
      }
      v4s pk;
#pragma unroll
      for (int r = 0; r < 4; r++) {
        int kap = tp * 16 + quad * 4 + r;
        int bit = (int)((mwc >> kap) & 1ull);
        float p = bit ? __expf(fmaf(s[r], 0.125f, -8.0f)) : MASKP;
        lacc += p;
        pk[r] = f2bf(p);
      }
      pa[tp] = pk;
    }

    // X += P @ V via 16x16x16 MFMA, P straight from registers.
    // B-frag: V[key=tp*16+quad*4+j][dk=u*16+l15] = Vs[(u*16+l15)*72 + tp*16+quad*4]
#pragma unroll
    for (int u = 0; u < 4; u++) {
      const short* vb_ = &Vs[(u * 16 + l15) * 72 + quad * 4];
#pragma unroll
      for (int tp = 0; tp < 4; tp++) {
        v4s bV = *(const v4s*)&vb_[tp * 16];
        accX[u] = mfma16x16(pa[tp], bV, accX[u]);
      }
    }
    mwc = mwn;
  }

  // complete l(q=l15): sum partial key-sums across the 4 quads
  lacc += __shfl_xor(lacc, 16);
  lacc += __shfl_xor(lacc, 32);

  // ---- split-K combine: fixed shift -> partials directly addable ----
  __syncthreads();                         // everyone done with K/V LDS
  if (half == 1) {
    float* c = CB + (wq * 64 + lane) * 17;
#pragma unroll
    for (int u = 0; u < 4; u++)
#pragma unroll
      for (int r = 0; r < 4; r++) c[u * 4 + r] = accX[u][r];
    c[16] = lacc;
  }
  __syncthreads();
  if (half == 0) {
    const float* c = CB + (wq * 64 + lane) * 17;
#pragma unroll
    for (int u = 0; u < 4; u++)
#pragma unroll
      for (int r = 0; r < 4; r++) accX[u][r] += c[u * 4 + r];
    float lsum = lacc + c[16];             // l for q = l15, all lanes valid
    float inv[4];
#pragma unroll
    for (int r = 0; r < 4; r++)
      inv[r] = 1.0f / __shfl(lsum, quad * 4 + r);   // l for q = quad*4+r
#pragma unroll
    for (int u = 0; u < 4; u++)
#pragma unroll
      for (int r = 0; r < 4; r++) {
        float x = accX[u][r] * inv[r];
        int srw = qrow + quad * 4 + r;
        XP[(b * S_LEN + srw) * D_MOD + h * D_K + u * 16 + l15] = f2bf(x);
      }
  }
}

// ---------------------------------------------------------------------------
// outproj: out = X @ Wo^T, all-bf16 inputs, VGPR-prefetch pipelined.
// ---------------------------------------------------------------------------
__global__ __launch_bounds__(256) void outproj_kernel(
    const short* __restrict__ XP, const short* __restrict__ Wob,
    float* __restrict__ out)
{
  const int m0 = blockIdx.x * 64, n0 = blockIdx.y * 64;
  const int tid = threadIdx.x;
  const int wave = tid >> 6, lane = tid & 63;
  const int quad = lane >> 4, l15 = lane & 15;
  const int wm = wave >> 1, wn = wave & 1;
  __shared__ short As[64][72];
  __shared__ short Bs[64][72];
  v4f acc[2][2];
#pragma unroll
  for (int i = 0; i < 2; i++)
#pragma unroll
    for (int j = 0; j < 2; j++) acc[i][j] = (v4f){0.f, 0.f, 0.f, 0.f};

  v8s a8[2], b8[2];
#pragma unroll
  for (int i = 0; i < 2; i++) {
    int fi = tid + i * 256, r = fi >> 3, c = (fi & 7) << 3;
    a8[i] = *(const v8s*)&XP[(m0 + r) * 512 + c];
    b8[i] = *(const v8s*)&Wob[(n0 + r) * 512 + c];
  }

  for (int kk = 0; kk < 512; kk += 64) {
    __syncthreads();
#pragma unroll
    for (int i = 0; i < 2; i++) {
      int fi = tid + i * 256, r = fi >> 3, c = (fi & 7) << 3;
      *(v8s*)&As[r][c] = a8[i];
      *(v8s*)&Bs[r][c] = b8[i];
    }
    __syncthreads();
    if (kk + 64 < 512) {
#pragma unroll
      for (int i = 0; i < 2; i++) {
        int fi = tid + i * 256, r = fi >> 3, c = (fi & 7) << 3;
        a8[i] = *(const v8s*)&XP[(m0 + r) * 512 + kk + 64 + c];
        b8[i] = *(const v8s*)&Wob[(n0 + r) * 512 + kk + 64 + c];
      }
    }
#pragma unroll
    for (int ms = 0; ms < 2; ms++)
#pragma unroll
      for (int ns = 0; ns < 2; ns++)
#pragma unroll
        for (int ks = 0; ks < 2; ks++) {
          union { v8s v; v4s h2[2]; } a, bb;
          a.h2[0]  = *(const v4s*)&As[wm * 32 + ms * 16 + l15][ks * 32 + quad * 8];
          a.h2[1]  = *(const v4s*)&As[wm * 32 + ms * 16 + l15][ks * 32 + quad * 8 + 4];
          bb.h2[0] = *(const v4s*)&Bs[wn * 32 + ns * 16 + l15][ks * 32 + quad * 8];
          bb.h2[1] = *(const v4s*)&Bs[wn * 32 + ns * 16 + l15][ks * 32 + quad * 8 + 4];
          acc[ms][ns] = mfma16(a.v, bb.v, acc[ms][ns]);
        }
  }
#pragma unroll
  for (int ms = 0; ms < 2; ms++)
#pragma unroll
    for (int ns = 0; ns < 2; ns++) {
      int n = n0 + wn * 32 + ns * 16 + l15;
#pragma unroll
      for (int r = 0; r < 4; r++) {
        int m = m0 + wm * 32 + ms * 16 + quad * 4 + r;
        out[m * 512 + n] = acc[ms][ns][r];
      }
    }
}

// ---------------------------------------------------------------------------
extern "C" void kernel_launch(void* const* d_in, const int* in_sizes, int n_in,
                              void* d_out, int out_size, void* d_ws, size_t ws_size,
                              hipStream_t stream) {
  const float* q  = (const float*)d_in[0];
  const float* k  = (const float*)d_in[1];
  const float* v  = (const float*)d_in[2];
  const int* mask = (const int*)d_in[3];
  const float* Wq = (const float*)d_in[4];
  const float* Wo = (const float*)d_in[5];
  float* out = (float*)d_out;
  char* ws = (char*)d_ws;
  // workspace layout:
  // 0:QP 4MB | 4:KP | 8:VT | 12:XP | 16:MP 0.5MB | 17:qb 4MB | 21:kb | 25:vb
  // 29:Wqb 0.5MB | 29.5:Wob 0.5MB   (total 30MB)
  short* QP = (short*)(ws);
  short* KP = (short*)(ws + (4u << 20));
  short* VT = (short*)(ws + (8u << 20));
  short* XP = (short*)(ws + (12u << 20));
  unsigned long long* MP = (unsigned long long*)(ws + (16u << 20));
  short* qb  = (short*)(ws + (17u << 20));
  short* kb  = (short*)(ws + (21u << 20));
  short* vb  = (short*)(ws + (25u << 20));
  short* Wqb = (short*)(ws + (29u << 20));
  short* Wob = (short*)(ws + (29u << 20) + (512u << 10));

  prep_kernel<<<dim3(6912), 256, 0, stream>>>(q, k, v, Wq, Wo, mask,
                                              qb, kb, vb, Wqb, Wob, MP);
  proj_kernel<<<dim3(64, 8, 3), 256, 0, stream>>>(qb, kb, vb, Wqb, QP, KP, VT);
  attn_kernel<<<dim3(32, N_H, 2), 512, 0, stream>>>(QP, KP, VT, MP, XP);
  outproj_kernel<<<dim3(64, 8, 1), 256, 0, stream>>>(XP, Wob, out);
}

// Round 7
// 151.921 us; speedup vs baseline: 1.0783x; 1.0783x over previous
//
#include <hip/hip_runtime.h>
#include <hip/hip_bf16.h>
#include <stdint.h>

// Problem: B=2, S=2048, D=512, H=8, DK=64
#define S_LEN 2048
#define D_MOD 512
#define N_H   8
#define D_K   64

typedef short v8s __attribute__((ext_vector_type(8)));
typedef short v4s __attribute__((ext_vector_type(4)));
typedef float v4f __attribute__((ext_vector_type(4)));

__device__ __forceinline__ short f2bf(float f) {        // RNE
  union { float f; unsigned u; } a; a.f = f;
  unsigned u = a.u;
  u += 0x7fffu + ((u >> 16) & 1u);
  return (short)(u >> 16);
}
__device__ __forceinline__ short f2bfh(float f) {       // round-half-up (p>=0)
  union { float f; unsigned u; } a; a.f = f;
  return (short)((a.u + 0x8000u) >> 16);
}

__device__ __forceinline__ v4f mfma16(v8s a, v8s b, v4f c) {
  return __builtin_amdgcn_mfma_f32_16x16x32_bf16(a, b, c, 0, 0, 0);
}
__device__ __forceinline__ v4f mfma16x16(v4s a, v4s b, v4f c) {
  return __builtin_amdgcn_mfma_f32_16x16x16bf16_1k(a, b, c, 0, 0, 0);
}

// ---------------------------------------------------------------------------
// proj (fused): z<3 -> C = A @ Wq^T for A in {q,k,v}, fp32 in, inline bf16 cvt,
// VGPR-prefetch pipelined (R4-proven). z==3 -> maskpack (bid<256) or Wo->bf16.
// ---------------------------------------------------------------------------
__global__ __launch_bounds__(256) void proj_kernel(
    const float* __restrict__ q, const float* __restrict__ k,
    const float* __restrict__ v, const float* __restrict__ Wq,
    const float* __restrict__ Wo, const int* __restrict__ mask,
    short* __restrict__ QP, short* __restrict__ KP, short* __restrict__ VT,
    short* __restrict__ Wob, unsigned long long* __restrict__ mp)
{
  const int z = blockIdx.z;
  const int tid = threadIdx.x;
  if (z == 3) {
    int bid = blockIdx.x * 8 + blockIdx.y;           // 0..511
    if (bid < 256) {                                  // maskpack: 64 cols/thread
      int id = bid * 256 + tid;                       // 0..65535
      const int4* m4 = (const int4*)(mask + (size_t)id * 64);
      unsigned long long w = 0ull;
#pragma unroll
      for (int j = 0; j < 16; j++) {
        int4 mv = m4[j];
        w |= (unsigned long long)(mv.x != 0) << (j * 4 + 0);
        w |= (unsigned long long)(mv.y != 0) << (j * 4 + 1);
        w |= (unsigned long long)(mv.z != 0) << (j * 4 + 2);
        w |= (unsigned long long)(mv.w != 0) << (j * 4 + 3);
      }
      mp[id] = w;
    } else {                                          // Wo cvt: 4 floats/thread
      unsigned off = (bid - 256) * 256 + tid;         // 0..65535
      float4 x = ((const float4*)Wo)[off];
      v4s p; p.x = f2bf(x.x); p.y = f2bf(x.y); p.z = f2bf(x.z); p.w = f2bf(x.w);
      ((v4s*)Wob)[off] = p;
    }
    return;
  }
  const float* __restrict__ A = (z == 0) ? q : ((z == 1) ? k : v);
  const int m0 = blockIdx.x * 64, n0 = blockIdx.y * 64;
  const int wave = tid >> 6, lane = tid & 63;
  const int quad = lane >> 4, l15 = lane & 15;
  const int wm = wave >> 1, wn = wave & 1;
  __shared__ short As[64][72];
  __shared__ short Bs[64][72];
  v4f acc[2][2];
#pragma unroll
  for (int i = 0; i < 2; i++)
#pragma unroll
    for (int j = 0; j < 2; j++) acc[i][j] = (v4f){0.f, 0.f, 0.f, 0.f};

  float4 a4[4], b4[4];
#pragma unroll
  for (int i = 0; i < 4; i++) {
    int fi = tid + i * 256, r = fi >> 4, c = (fi & 15) << 2;
    a4[i] = *(const float4*)&A[(m0 + r) * 512 + c];
    b4[i] = *(const float4*)&Wq[(n0 + r) * 512 + c];
  }

  for (int kk = 0; kk < 512; kk += 64) {
    __syncthreads();
#pragma unroll
    for (int i = 0; i < 4; i++) {
      int fi = tid + i * 256, r = fi >> 4, c = (fi & 15) << 2;
      v4s ap; ap.x = f2bf(a4[i].x); ap.y = f2bf(a4[i].y); ap.z = f2bf(a4[i].z); ap.w = f2bf(a4[i].w);
      *(v4s*)&As[r][c] = ap;
      v4s bp; bp.x = f2bf(b4[i].x); bp.y = f2bf(b4[i].y); bp.z = f2bf(b4[i].z); bp.w = f2bf(b4[i].w);
      *(v4s*)&Bs[r][c] = bp;
    }
    __syncthreads();
    if (kk + 64 < 512) {
#pragma unroll
      for (int i = 0; i < 4; i++) {
        int fi = tid + i * 256, r = fi >> 4, c = (fi & 15) << 2;
        a4[i] = *(const float4*)&A[(m0 + r) * 512 + kk + 64 + c];
        b4[i] = *(const float4*)&Wq[(n0 + r) * 512 + kk + 64 + c];
      }
    }
#pragma unroll
    for (int ms = 0; ms < 2; ms++)
#pragma unroll
      for (int ns = 0; ns < 2; ns++)
#pragma unroll
        for (int ks = 0; ks < 2; ks++) {
          union { v8s v; v4s h2[2]; } a, bb;
          a.h2[0]  = *(const v4s*)&As[wm * 32 + ms * 16 + l15][ks * 32 + quad * 8];
          a.h2[1]  = *(const v4s*)&As[wm * 32 + ms * 16 + l15][ks * 32 + quad * 8 + 4];
          bb.h2[0] = *(const v4s*)&Bs[wn * 32 + ns * 16 + l15][ks * 32 + quad * 8];
          bb.h2[1] = *(const v4s*)&Bs[wn * 32 + ns * 16 + l15][ks * 32 + quad * 8 + 4];
          acc[ms][ns] = mfma16(a.v, bb.v, acc[ms][ns]);
        }
  }
#pragma unroll
  for (int ms = 0; ms < 2; ms++)
#pragma unroll
    for (int ns = 0; ns < 2; ns++) {
      int mb = m0 + wm * 32 + ms * 16 + quad * 4;
      int n  = n0 + wn * 32 + ns * 16 + l15;
      int bI = mb >> 11, s = mb & 2047, hh = n >> 6, dk = n & 63;
      if (z == 2) {
        v4s pv;
        pv.x = f2bf(acc[ms][ns][0]); pv.y = f2bf(acc[ms][ns][1]);
        pv.z = f2bf(acc[ms][ns][2]); pv.w = f2bf(acc[ms][ns][3]);
        *(v4s*)&VT[((bI * N_H + hh) * D_K + dk) * S_LEN + s] = pv;
      } else {
        short* dst = (z == 0) ? QP : KP;
#pragma unroll
        for (int r = 0; r < 4; r++)
          dst[((bI * N_H + hh) * S_LEN + (s + r)) * D_K + dk] = f2bf(acc[ms][ns][r]);
      }
    }
}

// ---------------------------------------------------------------------------
// Flash attention v4: transposed-score, register P, fixed-shift softmax.
// 512 thr = 8 waves = 4 groups x 2 waves. Group g handles keys [g*512,(g+1)*512)
// in 8 tiles of 64, staging K/V tiles in group-private LDS. Each wave covers
// 32 q-rows (two 16-q B-operands) -> every LDS K/V read feeds 2 MFMAs.
// Row-sums via ones-MFMA (C-layout rows == accX rows -> zero shuffles).
// 4 partials combined through LDS (fixed shift -> directly addable).
// Grid: (32, H, B) = 512 blocks; LDS 73.7KB -> 2 blocks/CU.
// ---------------------------------------------------------------------------
__global__ __launch_bounds__(512, 4) void attn_kernel(
    const short* __restrict__ QP, const short* __restrict__ KP,
    const short* __restrict__ VT, const unsigned long long* __restrict__ mp,
    short* __restrict__ XP)
{
  const int h = blockIdx.y, b = blockIdx.z;
  const int tid = threadIdx.x;               // 0..511
  const int wave = tid >> 6;                 // 0..7
  const int grp  = wave >> 1;                // key-quarter 0..3
  const int wg   = wave & 1;                 // q-half (32 rows)
  const int lane = tid & 63;
  const int quad = lane >> 4, l15 = lane & 15;
  const short* Qh = QP + ((b * N_H + h) * S_LEN) * D_K;
  const short* Kh = KP + ((b * N_H + h) * S_LEN) * D_K;
  const short* Vh = VT + ((b * N_H + h) * D_K) * S_LEN;

  // LDS: Ks[4][64][72] + Vs[4][64][72] shorts = 73728 B.
  // Combine aliases [0, 3*128*41*4 = 62976) as float CB.
  __shared__ char smem[73728];
  short* Ks = (short*)smem + grp * 4608;
  short* Vs = (short*)(smem + 36864) + grp * 4608;
  float* CB = (float*)smem;

  const int qrow0 = blockIdx.x * 64 + wg * 32;   // wave's 32 q-rows
  const int t128 = tid & 127;                    // id within group
  const int srow = t128 >> 1;                    // 0..63
  const int sc   = (t128 & 1) * 32;              // short col base (4 chunks)
  const int ck0  = grp * 512;                    // group's key base

  v8s aQ[2][2];
#pragma unroll
  for (int g = 0; g < 2; g++)
#pragma unroll
    for (int ks = 0; ks < 2; ks++)
      aQ[g][ks] = *(const v8s*)&Qh[(qrow0 + g * 16 + l15) * D_K + ks * 32 + quad * 8];

  const float C1 = 0.18033688011112042f;    // 0.125 * log2(e)
  const float C2 = -11.541560327111707f;    // -8 * log2(e)
  const v4s ONES4 = {16256, 16256, 16256, 16256};   // bf16 1.0
  v4f accX[2][4], accL[2];
#pragma unroll
  for (int g = 0; g < 2; g++) {
    accL[g] = (v4f){0.f, 0.f, 0.f, 0.f};
#pragma unroll
    for (int u = 0; u < 4; u++) accX[g][u] = (v4f){0.f, 0.f, 0.f, 0.f};
  }

  // prefetch tile 0
  v8s kr[4], vr[4];
#pragma unroll
  for (int j = 0; j < 4; j++) {
    kr[j] = *(const v8s*)&Kh[(ck0 + srow) * D_K + sc + j * 8];
    vr[j] = *(const v8s*)&Vh[srow * S_LEN + ck0 + sc + j * 8];
  }
  unsigned long long mwc[2], mwn[2] = {0ull, 0ull};
#pragma unroll
  for (int g = 0; g < 2; g++)
    mwc[g] = mp[(qrow0 + g * 16 + l15) * 32 + grp * 8];

  for (int kt = 0; kt < 8; kt++) {
    __syncthreads();                        // prior compute done reading LDS
#pragma unroll
    for (int j = 0; j < 4; j++) {
      *(v8s*)&Ks[srow * 72 + sc + j * 8] = kr[j];
      *(v8s*)&Vs[srow * 72 + sc + j * 8] = vr[j];
    }
    __syncthreads();                        // tiles visible to the group

    if (kt + 1 < 8) {
      const int c1 = ck0 + (kt + 1) * 64;
#pragma unroll
      for (int j = 0; j < 4; j++) {
        kr[j] = *(const v8s*)&Kh[(c1 + srow) * D_K + sc + j * 8];
        vr[j] = *(const v8s*)&Vh[srow * S_LEN + c1 + sc + j * 8];
      }
#pragma unroll
      for (int g = 0; g < 2; g++)
        mwn[g] = mp[(qrow0 + g * 16 + l15) * 32 + grp * 8 + kt + 1];
    }

    // S^T = K @ Q^T per 16-key tile; exp -> bf16 A-frags (register P)
    v4s pa[2][4];
#pragma unroll
    for (int tp = 0; tp < 4; tp++) {
      v8s bK0 = *(const v8s*)&Ks[(tp * 16 + l15) * 72 + quad * 8];
      v8s bK1 = *(const v8s*)&Ks[(tp * 16 + l15) * 72 + 32 + quad * 8];
#pragma unroll
      for (int g = 0; g < 2; g++) {
        v4f s = mfma16(bK0, aQ[g][0], (v4f){0.f, 0.f, 0.f, 0.f});
        s = mfma16(bK1, aQ[g][1], s);
        unsigned mb = (unsigned)(mwc[g] >> (tp * 16 + quad * 4));
        v4s pk;
#pragma unroll
        for (int r = 0; r < 4; r++) {
          float se = ((mb >> r) & 1u) ? s[r] : 0.0f;   // masked: exp2(C2)=e^-8
          float p = __builtin_amdgcn_exp2f(fmaf(se, C1, C2));
          pk[r] = f2bfh(p);
        }
        pa[g][tp] = pk;
      }
    }

    // X += P @ V (each bV feeds both q-halves); L += P @ 1 (row sums on MFMA)
#pragma unroll
    for (int u = 0; u < 4; u++) {
      const short* vb_ = &Vs[(u * 16 + l15) * 72 + quad * 4];
#pragma unroll
      for (int tp = 0; tp < 4; tp++) {
        v4s bV = *(const v4s*)&vb_[tp * 16];
        accX[0][u] = mfma16x16(pa[0][tp], bV, accX[0][u]);
        accX[1][u] = mfma16x16(pa[1][tp], bV, accX[1][u]);
      }
    }
#pragma unroll
    for (int g = 0; g < 2; g++)
#pragma unroll
      for (int tp = 0; tp < 4; tp++)
        accL[g] = mfma16x16(pa[g][tp], ONES4, accL[g]);

    mwc[0] = mwn[0]; mwc[1] = mwn[1];
  }

  // ---- combine the 4 key-quarter partials (directly addable) ----
  __syncthreads();                          // all groups done with Ks/Vs
  if (grp > 0) {
    float* c = CB + ((grp - 1) * 128 + t128) * 41;
#pragma unroll
    for (int g = 0; g < 2; g++) {
#pragma unroll
      for (int u = 0; u < 4; u++)
#pragma unroll
        for (int r = 0; r < 4; r++) c[(g * 4 + u) * 4 + r] = accX[g][u][r];
#pragma unroll
      for (int r = 0; r < 4; r++) c[32 + g * 4 + r] = accL[g][r];
    }
  }
  __syncthreads();
  if (grp == 0) {
#pragma unroll
    for (int w = 0; w < 3; w++) {
      const float* c = CB + (w * 128 + t128) * 41;
#pragma unroll
      for (int g = 0; g < 2; g++) {
#pragma unroll
        for (int u = 0; u < 4; u++)
#pragma unroll
          for (int r = 0; r < 4; r++) accX[g][u][r] += c[(g * 4 + u) * 4 + r];
#pragma unroll
        for (int r = 0; r < 4; r++) accL[g][r] += c[32 + g * 4 + r];
      }
    }
#pragma unroll
    for (int g = 0; g < 2; g++) {
      float inv[4];
#pragma unroll
      for (int r = 0; r < 4; r++) inv[r] = 1.0f / accL[g][r];   // l for q=quad*4+r
#pragma unroll
      for (int u = 0; u < 4; u++)
#pragma unroll
        for (int r = 0; r < 4; r++) {
          int srw = qrow0 + g * 16 + quad * 4 + r;
          XP[(b * S_LEN + srw) * D_MOD + h * D_K + u * 16 + l15] =
              f2bf(accX[g][u][r] * inv[r]);
        }
    }
  }
}

// ---------------------------------------------------------------------------
// outproj: out = X @ Wo^T, bf16 inputs, VGPR-prefetch pipelined.
// ---------------------------------------------------------------------------
__global__ __launch_bounds__(256) void outproj_kernel(
    const short* __restrict__ XP, const short* __restrict__ Wob,
    float* __restrict__ out)
{
  const int m0 = blockIdx.x * 64, n0 = blockIdx.y * 64;
  const int tid = threadIdx.x;
  const int wave = tid >> 6, lane = tid & 63;
  const int quad = lane >> 4, l15 = lane & 15;
  const int wm = wave >> 1, wn = wave & 1;
  __shared__ short As[64][72];
  __shared__ short Bs[64][72];
  v4f acc[2][2];
#pragma unroll
  for (int i = 0; i < 2; i++)
#pragma unroll
    for (int j = 0; j < 2; j++) acc[i][j] = (v4f){0.f, 0.f, 0.f, 0.f};

  v8s a8[2], b8[2];
#pragma unroll
  for (int i = 0; i < 2; i++) {
    int fi = tid + i * 256, r = fi >> 3, c = (fi & 7) << 3;
    a8[i] = *(const v8s*)&XP[(m0 + r) * 512 + c];
    b8[i] = *(const v8s*)&Wob[(n0 + r) * 512 + c];
  }

  for (int kk = 0; kk < 512; kk += 64) {
    __syncthreads();
#pragma unroll
    for (int i = 0; i < 2; i++) {
      int fi = tid + i * 256, r = fi >> 3, c = (fi & 7) << 3;
      *(v8s*)&As[r][c] = a8[i];
      *(v8s*)&Bs[r][c] = b8[i];
    }
    __syncthreads();
    if (kk + 64 < 512) {
#pragma unroll
      for (int i = 0; i < 2; i++) {
        int fi = tid + i * 256, r = fi >> 3, c = (fi & 7) << 3;
        a8[i] = *(const v8s*)&XP[(m0 + r) * 512 + kk + 64 + c];
        b8[i] = *(const v8s*)&Wob[(n0 + r) * 512 + kk + 64 + c];
      }
    }
#pragma unroll
    for (int ms = 0; ms < 2; ms++)
#pragma unroll
      for (int ns = 0; ns < 2; ns++)
#pragma unroll
        for (int ks = 0; ks < 2; ks++) {
          union { v8s v; v4s h2[2]; } a, bb;
          a.h2[0]  = *(const v4s*)&As[wm * 32 + ms * 16 + l15][ks * 32 + quad * 8];
          a.h2[1]  = *(const v4s*)&As[wm * 32 + ms * 16 + l15][ks * 32 + quad * 8 + 4];
          bb.h2[0] = *(const v4s*)&Bs[wn * 32 + ns * 16 + l15][ks * 32 + quad * 8];
          bb.h2[1] = *(const v4s*)&Bs[wn * 32 + ns * 16 + l15][ks * 32 + quad * 8 + 4];
          acc[ms][ns] = mfma16(a.v, bb.v, acc[ms][ns]);
        }
  }
#pragma unroll
  for (int ms = 0; ms < 2; ms++)
#pragma unroll
    for (int ns = 0; ns < 2; ns++) {
      int n = n0 + wn * 32 + ns * 16 + l15;
#pragma unroll
      for (int r = 0; r < 4; r++) {
        int m = m0 + wm * 32 + ms * 16 + quad * 4 + r;
        out[m * 512 + n] = acc[ms][ns][r];
      }
    }
}

// ---------------------------------------------------------------------------
extern "C" void kernel_launch(void* const* d_in, const int* in_sizes, int n_in,
                              void* d_out, int out_size, void* d_ws, size_t ws_size,
                              hipStream_t stream) {
  const float* q  = (const float*)d_in[0];
  const float* k  = (const float*)d_in[1];
  const float* v  = (const float*)d_in[2];
  const int* mask = (const int*)d_in[3];
  const float* Wq = (const float*)d_in[4];
  const float* Wo = (const float*)d_in[5];
  float* out = (float*)d_out;
  char* ws = (char*)d_ws;
  // ws: 0:QP 4MB | 4:KP | 8:VT | 12:XP | 16:MP 0.5MB | 16.5:Wob 0.5MB
  short* QP = (short*)(ws);
  short* KP = (short*)(ws + (4u << 20));
  short* VT = (short*)(ws + (8u << 20));
  short* XP = (short*)(ws + (12u << 20));
  unsigned long long* MP = (unsigned long long*)(ws + (16u << 20));
  short* Wob = (short*)(ws + (16u << 20) + (512u << 10));

  proj_kernel<<<dim3(64, 8, 4), 256, 0, stream>>>(q, k, v, Wq, Wo, mask,
                                                  QP, KP, VT, Wob, MP);
  attn_kernel<<<dim3(32, N_H, 2), 512, 0, stream>>>(QP, KP, VT, MP, XP);
  outproj_kernel<<<dim3(64, 8, 1), 256, 0, stream>>>(XP, Wob, out);
}